// Round 3
// baseline (766.784 us; speedup 1.0000x reference)
//
#include <hip/hip_runtime.h>
#include <hip/hip_bf16.h>
#include <math.h>

#define TTOK 8192
#define DDIM 1024
#define HDIM 4096
#define NEXP 8
#define BMT 256              // M tile (slots padded per expert to 256)
#define MAXT 72              // sum ceil(c_e/256) <= 16384/256 + 8 = 72
#define MAXSLOTS (MAXT * BMT)

typedef __bf16 bf16x8 __attribute__((ext_vector_type(8)));
typedef float f32x4 __attribute__((ext_vector_type(4)));
typedef const void __attribute__((address_space(1))) *gvp_t;
typedef void __attribute__((address_space(3))) *lvp_t;

__device__ __forceinline__ void gload16(const void *g, void *l) {
  // async global->LDS: LDS dest = wave-uniform base + lane*16 (linear), 16B/lane
  __builtin_amdgcn_global_load_lds((gvp_t)g, (lvp_t)l, 16, 0, 0);
}

// ---------------- small utility kernels ----------------

__global__ __launch_bounds__(64) void zero_meta(int *counts, int *cursors, float *probsum) {
  int i = threadIdx.x;
  if (i < NEXP) { counts[i] = 0; cursors[i] = 0; probsum[i] = 0.f; }
}

__global__ __launch_bounds__(256) void convert_x(const float *__restrict__ x,
                                                 __hip_bfloat16 *__restrict__ xb) {
  size_t i = ((size_t)blockIdx.x * 256 + threadIdx.x) * 4;
  float4 v = *(const float4 *)(x + i);
  union { __hip_bfloat16 h[4]; uint2 u; } p;
  p.h[0] = __float2bfloat16(v.x);
  p.h[1] = __float2bfloat16(v.y);
  p.h[2] = __float2bfloat16(v.z);
  p.h[3] = __float2bfloat16(v.w);
  *(uint2 *)(xb + i) = p.u;
}

// src [E][R][C] fp32 -> dst [E][C][R] bf16, 64x64 LDS tiles
__global__ __launch_bounds__(256) void transpose_cvt(const float *__restrict__ src,
                                                     __hip_bfloat16 *__restrict__ dst,
                                                     int R, int C) {
  __shared__ float tile[64][65];
  const int e = blockIdx.z;
  const int rb = blockIdx.x * 64, cb = blockIdx.y * 64;
  const size_t base = (size_t)e * R * C;
  const int lx = threadIdx.x & 63, ly = threadIdx.x >> 6;
#pragma unroll
  for (int i = 0; i < 64; i += 4)
    tile[ly + i][lx] = src[base + (size_t)(rb + ly + i) * C + cb + lx];
  __syncthreads();
#pragma unroll
  for (int i = 0; i < 64; i += 4)
    dst[base + (size_t)(cb + ly + i) * R + rb + lx] = __float2bfloat16(tile[lx][ly + i]);
}

// ---------------- router (fp64 accumulation: exact top-2 match) ----------------
__global__ __launch_bounds__(256) void router_k(const float *__restrict__ x,
                                                const float *__restrict__ Wg,
                                                int *__restrict__ counts,
                                                float *__restrict__ probsum,
                                                int *__restrict__ tok_e,
                                                float *__restrict__ tok_w) {
  __shared__ float sprob[NEXP];
  __shared__ int scnt[NEXP];
  if (threadIdx.x < NEXP) { sprob[threadIdx.x] = 0.f; scnt[threadIdx.x] = 0; }
  __syncthreads();

  const int wid = threadIdx.x >> 6, lane = threadIdx.x & 63;
  const int t = blockIdx.x * 4 + wid;
  const float *xr = x + (size_t)t * DDIM;
  double acc[NEXP];
#pragma unroll
  for (int e = 0; e < NEXP; ++e) acc[e] = 0.0;
  for (int j = lane; j < DDIM; j += 64) {
    double xv = (double)xr[j];
    const float *wrow = Wg + j * NEXP;
#pragma unroll
    for (int e = 0; e < NEXP; ++e) acc[e] += xv * (double)wrow[e];
  }
#pragma unroll
  for (int e = 0; e < NEXP; ++e) {
#pragma unroll
    for (int off = 32; off > 0; off >>= 1) acc[e] += __shfl_xor(acc[e], off, 64);
  }
  if (lane == 0) {
    double mx = acc[0];
    for (int e = 1; e < NEXP; ++e) mx = acc[e] > mx ? acc[e] : mx;
    double p[NEXP], s = 0.0;
    for (int e = 0; e < NEXP; ++e) { p[e] = exp(acc[e] - mx); s += p[e]; }
    for (int e = 0; e < NEXP; ++e) p[e] /= s;
    int i0 = 0;
    for (int e = 1; e < NEXP; ++e) if (p[e] > p[i0]) i0 = e;
    int i1 = (i0 == 0) ? 1 : 0;
    for (int e = 0; e < NEXP; ++e) if (e != i0 && p[e] > p[i1]) i1 = e;
    tok_e[t] = i0 | (i1 << 16);
    tok_w[t] = (float)(p[i0] / (p[i0] + p[i1]));
    atomicAdd(&scnt[i0], 1);
    atomicAdd(&scnt[i1], 1);
    for (int e = 0; e < NEXP; ++e) atomicAdd(&sprob[e], (float)p[e]);
  }
  __syncthreads();
  if (threadIdx.x < NEXP) {
    atomicAdd(&counts[threadIdx.x], scnt[threadIdx.x]);
    atomicAdd(&probsum[threadIdx.x], sprob[threadIdx.x]);
  }
}

// ---------------- routing tables (pad each expert to 256) ----------------
__global__ __launch_bounds__(256) void offsets_k(const int *__restrict__ counts,
                                                 int *__restrict__ padoff,
                                                 int *__restrict__ tileexp,
                                                 int *__restrict__ total,
                                                 int *__restrict__ slot_tok,
                                                 float *__restrict__ slot_w) {
  __shared__ int sp[NEXP + 1];
  if (threadIdx.x == 0) {
    int off = 0, tt = 0;
    for (int e = 0; e < NEXP; ++e) {
      sp[e] = off;
      padoff[e] = off;
      int nt = (counts[e] + BMT - 1) >> 8;
      for (int i = 0; i < nt; ++i) tileexp[tt + i] = e;
      tt += nt;
      off += nt << 8;
    }
    sp[NEXP] = off;
    *total = tt;
  }
  __syncthreads();
  for (int e = 0; e < NEXP; ++e) {
    int s0 = sp[e] + counts[e], s1 = sp[e + 1];
    for (int s = s0 + (int)threadIdx.x; s < s1; s += 256) {
      slot_tok[s] = 0;   // pad: token 0 (safe to read), weight 0
      slot_w[s] = 0.f;
    }
  }
}

__global__ __launch_bounds__(256) void assign_k(const int *__restrict__ tok_e,
                                                const float *__restrict__ tok_w,
                                                const int *__restrict__ padoff,
                                                int *__restrict__ cursors,
                                                int *__restrict__ slot_tok,
                                                float *__restrict__ slot_w,
                                                int *__restrict__ slot_of) {
  const int t = blockIdx.x * 256 + threadIdx.x;
  const int ee = tok_e[t];
  const int e0 = ee & 0xffff, e1 = ee >> 16;
  const float w0 = tok_w[t];
  int p0 = atomicAdd(&cursors[e0], 1);
  int s0 = padoff[e0] + p0;
  slot_tok[s0] = t; slot_w[s0] = w0; slot_of[2 * t] = s0;
  int p1 = atomicAdd(&cursors[e1], 1);
  int s1 = padoff[e1] + p1;
  slot_tok[s1] = t; slot_w[s1] = 1.0f - w0; slot_of[2 * t + 1] = s1;
}

// ---------------- grouped GEMM, m201-geometry 4-phase pipeline ----------------
// BM=256 fixed. Template: BN_ (256 or 128), WRW_ (waves in M: 2 or 4).
// Per-wave C tile: (256/WRW_) x 64.  B-fragments register-cached per K-tile.
// Pipeline: whole next K-tile staged at tile start (lead = 4 phases);
// boundary sync = vmcnt(0)+barrier (robust to any extra VMEM the compiler adds).
template <int KDIM_, int NDIM_, int BN_, int WRW_, bool GELU_, bool GATHER_>
__global__ __launch_bounds__(512, 2) void moe_gemm8(
    const __hip_bfloat16 *__restrict__ A, const __hip_bfloat16 *__restrict__ Bw,
    const float *__restrict__ bias, __hip_bfloat16 *__restrict__ Cout,
    const int *__restrict__ slot_token, const int *__restrict__ tile_expert,
    const int *__restrict__ total_tiles) {
  constexpr int WCW = 8 / WRW_;     // waves in N
  constexpr int PWM = 256 / WRW_;   // per-wave rows
  constexpr int MF = PWM / 16;      // m-frags per wave (8 or 4)
  constexpr int NBL = BN_ / 64;     // B stage chunks (4 or 2)
  constexpr int ABUF = 32768;
  constexpr int BBUF = BN_ * 128;
  static_assert(BN_ / WCW == 64, "per-wave N must be 64");

  __shared__ __align__(16) char lsA[2 * ABUF];
  __shared__ __align__(16) char lsB[2 * BBUF];

  const int tile = blockIdx.x;
  if (tile >= *total_tiles) return;
  const int e = tile_expert[tile];
  const int ncol = blockIdx.y * BN_;
  const int tid = threadIdx.x, wid = tid >> 6, lane = tid & 63;

  // ---- staging: each gload16 covers 8 rows x 128B; source col pre-swizzled (T2) ----
  const int sr = lane >> 3;               // row 0..7 within 8-row chunk
  const int scs = ((lane & 7) ^ sr) * 8;  // swizzled 16B slot (elements)
  const __hip_bfloat16 *Bb = Bw + (size_t)e * ((size_t)NDIM_ * KDIM_);
  const __hip_bfloat16 *ap[4], *bp[NBL];
#pragma unroll
  for (int c = 0; c < 4; ++c) {
    int r = tile * 256 + c * 64 + wid * 8 + sr;
    int row = GATHER_ ? slot_token[r] : r;
    ap[c] = A + (size_t)row * KDIM_ + scs;
  }
#pragma unroll
  for (int c = 0; c < NBL; ++c)
    bp[c] = Bb + (size_t)(ncol + c * 64 + wid * 8 + sr) * KDIM_ + scs;
  const int sdst = wid * 1024;  // +c*8192 (+lane*16 implicit)

  // ---- fragment read offsets (read-side swizzle matches source pre-swizzle) ----
  const int wr = wid / WCW, wc = wid % WCW;
  const int ln15 = lane & 15, g4 = lane >> 4;
  int abase[2], bbase[2];
#pragma unroll
  for (int kc = 0; kc < 2; ++kc) {
    const int xsl = ((kc * 4 + g4) ^ (ln15 & 7)) << 4;
    abase[kc] = (wr * PWM + ln15) * 128 + xsl;
    bbase[kc] = (wc * 64 + ln15) * 128 + xsl;
  }

  f32x4 acc[MF][4] = {};
  constexpr int nkt = KDIM_ / 64;

  auto STAGE = [&](int buf, int kt) {
#pragma unroll
    for (int c = 0; c < 4; ++c)
      gload16(ap[c] + kt * 64, lsA + buf * ABUF + c * 8192 + sdst);
#pragma unroll
    for (int c = 0; c < NBL; ++c)
      gload16(bp[c] + kt * 64, lsB + buf * BBUF + c * 8192 + sdst);
  };

  STAGE(0, 0);
  for (int kt = 0; kt < nkt; ++kt) {
    const int b = kt & 1;
    // ---- tile boundary: own loads landed, then all waves' loads landed ----
    asm volatile("s_waitcnt vmcnt(0)" ::: "memory");
    __builtin_amdgcn_s_barrier();
    if (kt + 1 < nkt) STAGE(b ^ 1, kt + 1);  // lead = 4 phases
    // ---- B fragments for whole K-tile (register-cached) ----
    bf16x8 bfr[4][2];
#pragma unroll
    for (int ni = 0; ni < 4; ++ni)
#pragma unroll
      for (int kc = 0; kc < 2; ++kc)
        bfr[ni][kc] = *(const bf16x8 *)(lsB + b * BBUF + bbase[kc] + ni * 2048);
    // ---- phases: (mh, kc), 16 MFMA each ----
#pragma unroll
    for (int ph = 0; ph < (MF / 4) * 2; ++ph) {
      const int mh = (MF == 8) ? (ph & 1) : 0;
      const int kc = (MF == 8) ? (ph >> 1) : ph;
      bf16x8 af[4];
#pragma unroll
      for (int m = 0; m < 4; ++m)
        af[m] = *(const bf16x8 *)(lsA + b * ABUF + abase[kc] + (mh * 4 + m) * 2048);
      asm volatile("s_waitcnt lgkmcnt(0)" ::: "memory");
      __builtin_amdgcn_sched_barrier(0);  // rule #18: keep MFMA below the wait
      __builtin_amdgcn_s_setprio(1);
#pragma unroll
      for (int m = 0; m < 4; ++m)
#pragma unroll
        for (int n = 0; n < 4; ++n)
          acc[mh * 4 + m][n] = __builtin_amdgcn_mfma_f32_16x16x32_bf16(
              af[m], bfr[n][kc], acc[mh * 4 + m][n], 0, 0, 0);
      __builtin_amdgcn_s_setprio(0);
      __builtin_amdgcn_s_barrier();
    }
  }

  // ---- epilogue: C/D layout col=lane&15, row=(lane>>4)*4+reg [m89] ----
  const float *be = bias + (size_t)e * NDIM_;
  const int colb = ncol + wc * 64 + ln15;
  float bv[4];
#pragma unroll
  for (int ni = 0; ni < 4; ++ni) bv[ni] = be[colb + ni * 16];
#pragma unroll
  for (int mi = 0; mi < MF; ++mi) {
    const int row0 = tile * 256 + wr * PWM + mi * 16 + g4 * 4;
#pragma unroll
    for (int ni = 0; ni < 4; ++ni) {
      const int col = colb + ni * 16;
#pragma unroll
      for (int r = 0; r < 4; ++r) {
        float v = acc[mi][ni][r] + bv[ni];
        if constexpr (GELU_) v = 0.5f * v * (1.0f + erff(v * 0.70710678118654752f));
        Cout[(size_t)(row0 + r) * NDIM_ + col] = __float2bfloat16(v);
      }
    }
  }
}

// ---------------- combine + aux ----------------
__global__ __launch_bounds__(256) void combine_k(const __hip_bfloat16 *__restrict__ yb,
                                                 const int *__restrict__ slot_of,
                                                 const float *__restrict__ slot_w,
                                                 float *__restrict__ out) {
  const int t = blockIdx.x;
  const int s0 = slot_of[2 * t], s1 = slot_of[2 * t + 1];
  const float w0 = slot_w[s0], w1 = slot_w[s1];
  const unsigned short *y = (const unsigned short *)yb;
  const int c = threadIdx.x * 4;
  ushort4 a = *(const ushort4 *)(y + (size_t)s0 * DDIM + c);
  ushort4 b = *(const ushort4 *)(y + (size_t)s1 * DDIM + c);
  float4 r;
  r.x = w0 * __uint_as_float((unsigned)a.x << 16) + w1 * __uint_as_float((unsigned)b.x << 16);
  r.y = w0 * __uint_as_float((unsigned)a.y << 16) + w1 * __uint_as_float((unsigned)b.y << 16);
  r.z = w0 * __uint_as_float((unsigned)a.z << 16) + w1 * __uint_as_float((unsigned)b.z << 16);
  r.w = w0 * __uint_as_float((unsigned)a.w << 16) + w1 * __uint_as_float((unsigned)b.w << 16);
  *(float4 *)(out + (size_t)t * DDIM + c) = r;
}

__global__ __launch_bounds__(64) void aux_k(const int *__restrict__ counts,
                                            const float *__restrict__ probsum,
                                            float *__restrict__ outp) {
  if (threadIdx.x == 0) {
    double s = 0.0;
    for (int e = 0; e < NEXP; ++e)
      s += ((double)counts[e] / (double)TTOK) * ((double)probsum[e] / (double)TTOK);
    *outp = (float)((double)NEXP * s);
  }
}

// ---------------- launch ----------------
extern "C" void kernel_launch(void *const *d_in, const int *in_sizes, int n_in,
                              void *d_out, int out_size, void *d_ws, size_t ws_size,
                              hipStream_t stream) {
  const float *x  = (const float *)d_in[0];
  const float *Wg = (const float *)d_in[1];
  const float *W1 = (const float *)d_in[2];
  const float *b1 = (const float *)d_in[3];
  const float *W2 = (const float *)d_in[4];
  const float *b2 = (const float *)d_in[5];
  float *out = (float *)d_out;

  char *ws = (char *)d_ws;
  const size_t MB = 1ull << 20;
  // meta (< 1 MiB)
  int   *counts   = (int *)(ws + 0);
  int   *cursors  = (int *)(ws + 64);
  int   *padoff   = (int *)(ws + 128);
  int   *tileexp  = (int *)(ws + 192);      // 72 ints
  int   *total    = (int *)(ws + 768);
  float *probsum  = (float *)(ws + 832);
  int   *tok_e    = (int *)(ws + 4096);     // T ints
  float *tok_w    = (float *)(ws + 36864);  // T floats
  int   *slot_tok = (int *)(ws + 69632);    // MAXSLOTS ints (72KB)
  float *slot_w   = (float *)(ws + 147456); // MAXSLOTS floats
  int   *slot_of  = (int *)(ws + 225280);   // 2T ints
  // data regions (peak 261 MiB)
  __hip_bfloat16 *xb  = (__hip_bfloat16 *)(ws + 1 * MB);    // 16 MiB  [T][D]
  __hip_bfloat16 *w1t = (__hip_bfloat16 *)(ws + 17 * MB);   // 64 MiB  [E][H][D]
  __hip_bfloat16 *hb  = (__hip_bfloat16 *)(ws + 81 * MB);   // 144 MiB [MAXSLOTS][H] (ends exactly at 225MiB)
  __hip_bfloat16 *w2t = (__hip_bfloat16 *)(ws + 1 * MB);    // 64 MiB  [E][D][H] (after GEMM1; xb/w1t dead)
  __hip_bfloat16 *yb  = (__hip_bfloat16 *)(ws + 225 * MB);  // 36 MiB  [MAXSLOTS][D]

  zero_meta<<<1, 64, 0, stream>>>(counts, cursors, probsum);
  convert_x<<<8192, 256, 0, stream>>>(x, xb);
  transpose_cvt<<<dim3(16, 64, 8), 256, 0, stream>>>(W1, w1t, DDIM, HDIM);
  router_k<<<TTOK / 4, 256, 0, stream>>>(x, Wg, counts, probsum, tok_e, tok_w);
  offsets_k<<<1, 256, 0, stream>>>(counts, padoff, tileexp, total, slot_tok, slot_w);
  assign_k<<<TTOK / 256, 256, 0, stream>>>(tok_e, tok_w, padoff, cursors, slot_tok, slot_w, slot_of);
  // GEMM1: h = gelu(x @ W1 + b1), BN=256, waves 2x4 (per-wave 128x64)
  moe_gemm8<DDIM, HDIM, 256, 2, true, true><<<dim3(MAXT, HDIM / 256), 512, 0, stream>>>(
      xb, w1t, b1, hb, slot_tok, tileexp, total);
  transpose_cvt<<<dim3(64, 16, 8), 256, 0, stream>>>(W2, w2t, HDIM, DDIM);
  // GEMM2: y = h @ W2 + b2, BN=128, waves 4x2 (per-wave 64x64)
  moe_gemm8<HDIM, DDIM, 128, 4, false, false><<<dim3(MAXT, DDIM / 128), 512, 0, stream>>>(
      hb, w2t, b2, yb, slot_tok, tileexp, total);
  combine_k<<<TTOK, 256, 0, stream>>>(yb, slot_of, slot_w, out);
  aux_k<<<1, 64, 0, stream>>>(counts, probsum, out + (size_t)TTOK * DDIM);
}

// Round 4
// 758.529 us; speedup vs baseline: 1.0109x; 1.0109x over previous
//
#include <hip/hip_runtime.h>
#include <hip/hip_bf16.h>
#include <math.h>

#define TTOK 8192
#define DDIM 1024
#define HDIM 4096
#define NEXP 8
#define BMT 256              // slot padding granularity per expert
#define MAXT 72              // sum ceil(c_e/256) <= 16384/256 + 8
#define MAXSLOTS (MAXT * BMT)

typedef __bf16 bf16x8 __attribute__((ext_vector_type(8)));
typedef float f32x4 __attribute__((ext_vector_type(4)));
typedef const void __attribute__((address_space(1))) *gvp_t;
typedef void __attribute__((address_space(3))) *lvp_t;

__device__ __forceinline__ void gload16(const void *g, void *l) {
  __builtin_amdgcn_global_load_lds((gvp_t)g, (lvp_t)l, 16, 0, 0);
}
__device__ __forceinline__ void bar() {
  asm volatile("" ::: "memory");
  __builtin_amdgcn_s_barrier();
  asm volatile("" ::: "memory");
}
template <int N> __device__ __forceinline__ void wait_vm() {
  if constexpr (N == 0) asm volatile("s_waitcnt vmcnt(0)" ::: "memory");
  else if constexpr (N == 2) asm volatile("s_waitcnt vmcnt(2)" ::: "memory");
  else if constexpr (N == 4) asm volatile("s_waitcnt vmcnt(4)" ::: "memory");
  __builtin_amdgcn_sched_barrier(0);
}
template <int N> __device__ __forceinline__ void wait_lgkm() {
  if constexpr (N == 0) asm volatile("s_waitcnt lgkmcnt(0)" ::: "memory");
  else if constexpr (N == 4) asm volatile("s_waitcnt lgkmcnt(4)" ::: "memory");
  __builtin_amdgcn_sched_barrier(0);  // rule #18: keep MFMA below the wait
}

// ---------------- small utility kernels ----------------

__global__ __launch_bounds__(64) void zero_meta(int *counts, int *cursors, float *probsum) {
  int i = threadIdx.x;
  if (i < NEXP) { counts[i] = 0; cursors[i] = 0; probsum[i] = 0.f; }
}

__global__ __launch_bounds__(256) void convert_x(const float *__restrict__ x,
                                                 __hip_bfloat16 *__restrict__ xb) {
  size_t i = ((size_t)blockIdx.x * 256 + threadIdx.x) * 4;
  float4 v = *(const float4 *)(x + i);
  union { __hip_bfloat16 h[4]; uint2 u; } p;
  p.h[0] = __float2bfloat16(v.x);
  p.h[1] = __float2bfloat16(v.y);
  p.h[2] = __float2bfloat16(v.z);
  p.h[3] = __float2bfloat16(v.w);
  *(uint2 *)(xb + i) = p.u;
}

// src [E][R][C] fp32 -> dst [E][C][R] bf16, 64x64 LDS tiles
__global__ __launch_bounds__(256) void transpose_cvt(const float *__restrict__ src,
                                                     __hip_bfloat16 *__restrict__ dst,
                                                     int R, int C) {
  __shared__ float tile[64][65];
  const int e = blockIdx.z;
  const int rb = blockIdx.x * 64, cb = blockIdx.y * 64;
  const size_t base = (size_t)e * R * C;
  const int lx = threadIdx.x & 63, ly = threadIdx.x >> 6;
#pragma unroll
  for (int i = 0; i < 64; i += 4)
    tile[ly + i][lx] = src[base + (size_t)(rb + ly + i) * C + cb + lx];
  __syncthreads();
#pragma unroll
  for (int i = 0; i < 64; i += 4)
    dst[base + (size_t)(cb + ly + i) * R + rb + lx] = __float2bfloat16(tile[lx][ly + i]);
}

// ---------------- router (fp64 accumulation: exact top-2 match) ----------------
__global__ __launch_bounds__(256) void router_k(const float *__restrict__ x,
                                                const float *__restrict__ Wg,
                                                int *__restrict__ counts,
                                                float *__restrict__ probsum,
                                                int *__restrict__ tok_e,
                                                float *__restrict__ tok_w) {
  __shared__ float sprob[NEXP];
  __shared__ int scnt[NEXP];
  if (threadIdx.x < NEXP) { sprob[threadIdx.x] = 0.f; scnt[threadIdx.x] = 0; }
  __syncthreads();

  const int wid = threadIdx.x >> 6, lane = threadIdx.x & 63;
  const int t = blockIdx.x * 4 + wid;
  const float *xr = x + (size_t)t * DDIM;
  double acc[NEXP];
#pragma unroll
  for (int e = 0; e < NEXP; ++e) acc[e] = 0.0;
  for (int j = lane; j < DDIM; j += 64) {
    double xv = (double)xr[j];
    const float *wrow = Wg + j * NEXP;
#pragma unroll
    for (int e = 0; e < NEXP; ++e) acc[e] += xv * (double)wrow[e];
  }
#pragma unroll
  for (int e = 0; e < NEXP; ++e) {
#pragma unroll
    for (int off = 32; off > 0; off >>= 1) acc[e] += __shfl_xor(acc[e], off, 64);
  }
  if (lane == 0) {
    double mx = acc[0];
    for (int e = 1; e < NEXP; ++e) mx = acc[e] > mx ? acc[e] : mx;
    double p[NEXP], s = 0.0;
    for (int e = 0; e < NEXP; ++e) { p[e] = exp(acc[e] - mx); s += p[e]; }
    for (int e = 0; e < NEXP; ++e) p[e] /= s;
    int i0 = 0;
    for (int e = 1; e < NEXP; ++e) if (p[e] > p[i0]) i0 = e;
    int i1 = (i0 == 0) ? 1 : 0;
    for (int e = 0; e < NEXP; ++e) if (e != i0 && p[e] > p[i1]) i1 = e;
    tok_e[t] = i0 | (i1 << 16);
    tok_w[t] = (float)(p[i0] / (p[i0] + p[i1]));
    atomicAdd(&scnt[i0], 1);
    atomicAdd(&scnt[i1], 1);
    for (int e = 0; e < NEXP; ++e) atomicAdd(&sprob[e], (float)p[e]);
  }
  __syncthreads();
  if (threadIdx.x < NEXP) {
    atomicAdd(&counts[threadIdx.x], scnt[threadIdx.x]);
    atomicAdd(&probsum[threadIdx.x], sprob[threadIdx.x]);
  }
}

// ---------------- routing tables (pad each expert to 256) ----------------
__global__ __launch_bounds__(256) void offsets_k(const int *__restrict__ counts,
                                                 int *__restrict__ padoff,
                                                 int *__restrict__ tileexp,
                                                 int *__restrict__ total,
                                                 int *__restrict__ slot_tok,
                                                 float *__restrict__ slot_w) {
  __shared__ int sp[NEXP + 1];
  if (threadIdx.x == 0) {
    int off = 0, tt = 0;
    for (int e = 0; e < NEXP; ++e) {
      sp[e] = off;
      padoff[e] = off;
      int nt = (counts[e] + BMT - 1) >> 8;
      for (int i = 0; i < nt; ++i) tileexp[tt + i] = e;
      tt += nt;
      off += nt << 8;
    }
    sp[NEXP] = off;
    *total = tt;
  }
  __syncthreads();
  for (int e = 0; e < NEXP; ++e) {
    int s0 = sp[e] + counts[e], s1 = sp[e + 1];
    for (int s = s0 + (int)threadIdx.x; s < s1; s += 256) {
      slot_tok[s] = 0;   // pad: token 0 (safe to read), weight 0
      slot_w[s] = 0.f;
    }
  }
}

__global__ __launch_bounds__(256) void assign_k(const int *__restrict__ tok_e,
                                                const float *__restrict__ tok_w,
                                                const int *__restrict__ padoff,
                                                int *__restrict__ cursors,
                                                int *__restrict__ slot_tok,
                                                float *__restrict__ slot_w,
                                                int *__restrict__ slot_of) {
  const int t = blockIdx.x * 256 + threadIdx.x;
  const int ee = tok_e[t];
  const int e0 = ee & 0xffff, e1 = ee >> 16;
  const float w0 = tok_w[t];
  int p0 = atomicAdd(&cursors[e0], 1);
  int s0 = padoff[e0] + p0;
  slot_tok[s0] = t; slot_w[s0] = w0; slot_of[2 * t] = s0;
  int p1 = atomicAdd(&cursors[e1], 1);
  int s1 = padoff[e1] + p1;
  slot_tok[s1] = t; slot_w[s1] = 1.0f - w0; slot_of[2 * t + 1] = s1;
}

// ---------------- grouped GEMM, m201-faithful 4-phase counted-vmcnt pipeline ----
// BN=256 fixed, 8 waves (2x4), per-wave (BM_/2)x64.
// Stage order per K-tile: [B0,B1][B2,B3][A-even][A-odd]; counted waits at ph0/ph1
// only (vmcnt 4/2, never 0 mid-loop). ds_reads software-pipelined one phase ahead
// where residency allows. T2 source-preswizzle + read swizzle (conflict-free).
template <int BM_, int KD_, int ND_, bool GELU_, bool GATHER_, int TSH_>
__global__ __launch_bounds__(512, 2) void moe_gemmx(
    const __hip_bfloat16 *__restrict__ A, const __hip_bfloat16 *__restrict__ Bw,
    const float *__restrict__ bias, __hip_bfloat16 *__restrict__ Cout,
    const int *__restrict__ slot_token, const int *__restrict__ tile_expert,
    const int *__restrict__ total_tiles) {
  constexpr int MF = BM_ / 32;    // m-frags per wave (8|4)
  constexpr int MRP = MF / 2;     // m-frags per phase (4|2)
  constexpr int PWM = BM_ / 2;    // per-wave rows
  constexpr int AISS = BM_ / 64;  // A stage chunks (4|2)
  constexpr int ABUF = BM_ * 128;
  constexpr int BBUF = 32768;
  constexpr int nkt = KD_ / 64;
  __shared__ __align__(16) char lsA[2 * ABUF];
  __shared__ __align__(16) char lsB[2 * BBUF];

  const int tile = blockIdx.x;
  if (tile >= ((*total_tiles) << TSH_)) return;
  const int e = tile_expert[tile >> TSH_];
  const int ncol = blockIdx.y * 256;
  const int tid = threadIdx.x, wid = tid >> 6, lane = tid & 63;

  // staging: chunk c = 64 rows x 128B; source col pre-swizzled (T2)
  const int sr = lane >> 3;
  const int scs = ((lane & 7) ^ sr) * 8;
  const __hip_bfloat16 *Bb = Bw + (size_t)e * ((size_t)ND_ * KD_);
  const __hip_bfloat16 *ap[AISS], *bp[4];
#pragma unroll
  for (int c = 0; c < AISS; ++c) {
    int r = tile * BM_ + c * 64 + wid * 8 + sr;
    int row = GATHER_ ? slot_token[r] : r;
    ap[c] = A + (size_t)row * KD_ + scs;
  }
#pragma unroll
  for (int c = 0; c < 4; ++c)
    bp[c] = Bb + (size_t)(ncol + c * 64 + wid * 8 + sr) * KD_ + scs;
  const int sdst = wid * 1024;

  // fragment read offsets (read swizzle matches source pre-swizzle)
  const int wr = wid >> 2, wc = wid & 3;
  const int ln15 = lane & 15, g4 = lane >> 4;
  int abase[2], bbase[2];
#pragma unroll
  for (int kc = 0; kc < 2; ++kc) {
    const int xsl = ((kc * 4 + g4) ^ (ln15 & 7)) << 4;
    abase[kc] = (wr * PWM + ln15) * 128 + xsl;
    bbase[kc] = (wc * 64 + ln15) * 128 + xsl;
  }

  auto stA = [&](int buf, int kt, int c) {
    gload16(ap[c] + kt * 64, lsA + buf * ABUF + c * 8192 + sdst);
  };
  auto stB = [&](int buf, int kt, int c) {
    gload16(bp[c] + kt * 64, lsB + buf * BBUF + c * 8192 + sdst);
  };
  auto SP = [&](int buf, int kt, int p) {  // stage pair p (p literal at call site)
    if (p == 0) { stB(buf, kt, 0); stB(buf, kt, 1); }
    else if (p == 1) { stB(buf, kt, 2); stB(buf, kt, 3); }
    else if (p == 2) {
      if constexpr (MF == 8) { stA(buf, kt, 0); stA(buf, kt, 2); }
      else { stA(buf, kt, 0); stA(buf, kt, 1); }
    } else {
      if constexpr (MF == 8) { stA(buf, kt, 1); stA(buf, kt, 3); }
    }
  };

  f32x4 acc[MF][4] = {};
  bf16x8 afE[MRP], afO[MRP], bfr[4][2];

#define RD_A(dst, mh, kc)                                                        \
  _Pragma("unroll") for (int m_ = 0; m_ < MRP; ++m_)                             \
      dst[m_] = *(const bf16x8 *)(lsA + b * ABUF + abase[kc] + ((mh) * MRP + m_) * 2048);
#define RD_B(kc)                                                                 \
  _Pragma("unroll") for (int n_ = 0; n_ < 4; ++n_)                               \
      bfr[n_][kc] = *(const bf16x8 *)(lsB + b * BBUF + bbase[kc] + n_ * 2048);
#define MM(mh, kc, af)                                                           \
  __builtin_amdgcn_s_setprio(1);                                                 \
  _Pragma("unroll") for (int m_ = 0; m_ < MRP; ++m_)                             \
      _Pragma("unroll") for (int n_ = 0; n_ < 4; ++n_)                           \
          acc[(mh) * MRP + m_][n_] = __builtin_amdgcn_mfma_f32_16x16x32_bf16(    \
              af[m_], bfr[n_][kc], acc[(mh) * MRP + m_][n_], 0, 0, 0);           \
  __builtin_amdgcn_s_setprio(0);

  // ---- prologue: stage tile 0 in consumption order ----
  wait_vm<0>();  // retire pointer/gather loads so vmcnt counting is exact
  SP(0, 0, 0); SP(0, 0, 1); SP(0, 0, 2);
  if constexpr (MF == 8) SP(0, 0, 3);

  for (int kt = 0; kt < nkt; ++kt) {
    const int b = kt & 1, ob = b ^ 1;
    const bool last = (kt == nkt - 1);
    // ---------- phase 0 : (kc0, mh0) ----------
    if (!last) { SP(ob, kt + 1, 0); wait_vm<(MF == 8) ? 4 : 2>(); }
    else       { wait_vm<(MF == 8) ? 2 : 0>(); }
    bar();
    RD_B(0); RD_A(afE, 0, 0); RD_B(1);
    wait_lgkm<4>();            // B(kc0)+A(ph0) done; B(kc1) still in flight
    MM(0, 0, afE);
    if constexpr (MF == 4) { RD_A(afO, 1, 0); }  // whole tile resident (MF4)
    bar();
    // ---------- phase 1 : (kc0, mh1) ----------
    if (!last) SP(ob, kt + 1, 1);
    if constexpr (MF == 8) { if (!last) wait_vm<4>(); else wait_vm<0>(); }
    bar();
    if constexpr (MF == 8) { RD_A(afO, 1, 0); }
    wait_lgkm<0>();
    MM(1, 0, afO);
    RD_A(afE, 0, 1);           // read-ahead ph2 (resident)
    bar();
    // ---------- phase 2 : (kc1, mh0) ----------
    if (!last) SP(ob, kt + 1, 2);
    bar();
    wait_lgkm<0>();
    MM(0, 1, afE);
    RD_A(afO, 1, 1);           // read-ahead ph3 (resident)
    bar();
    // ---------- phase 3 : (kc1, mh1) ----------
    if constexpr (MF == 8) { if (!last) SP(ob, kt + 1, 3); }
    bar();
    wait_lgkm<0>();
    MM(1, 1, afO);
    bar();
  }
#undef RD_A
#undef RD_B
#undef MM

  // ---- epilogue: C/D layout col=lane&15, row=(lane>>4)*4+reg [m89] ----
  const float *be = bias + (size_t)e * ND_;
  const int colb = ncol + wc * 64 + ln15;
  float bv[4];
#pragma unroll
  for (int ni = 0; ni < 4; ++ni) bv[ni] = be[colb + ni * 16];
#pragma unroll
  for (int mi = 0; mi < MF; ++mi) {
    const int row0 = tile * BM_ + wr * PWM + mi * 16 + g4 * 4;
#pragma unroll
    for (int ni = 0; ni < 4; ++ni) {
      const int col = colb + ni * 16;
#pragma unroll
      for (int r = 0; r < 4; ++r) {
        float v = acc[mi][ni][r] + bv[ni];
        if constexpr (GELU_) v = 0.5f * v * (1.0f + erff(v * 0.70710678118654752f));
        Cout[(size_t)(row0 + r) * ND_ + col] = __float2bfloat16(v);
      }
    }
  }
}

// ---------------- combine + aux ----------------
__global__ __launch_bounds__(256) void combine_k(const __hip_bfloat16 *__restrict__ yb,
                                                 const int *__restrict__ slot_of,
                                                 const float *__restrict__ slot_w,
                                                 float *__restrict__ out) {
  const int t = blockIdx.x;
  const int s0 = slot_of[2 * t], s1 = slot_of[2 * t + 1];
  const float w0 = slot_w[s0], w1 = slot_w[s1];
  const unsigned short *y = (const unsigned short *)yb;
  const int c = threadIdx.x * 4;
  ushort4 a = *(const ushort4 *)(y + (size_t)s0 * DDIM + c);
  ushort4 b = *(const ushort4 *)(y + (size_t)s1 * DDIM + c);
  float4 r;
  r.x = w0 * __uint_as_float((unsigned)a.x << 16) + w1 * __uint_as_float((unsigned)b.x << 16);
  r.y = w0 * __uint_as_float((unsigned)a.y << 16) + w1 * __uint_as_float((unsigned)b.y << 16);
  r.z = w0 * __uint_as_float((unsigned)a.z << 16) + w1 * __uint_as_float((unsigned)b.z << 16);
  r.w = w0 * __uint_as_float((unsigned)a.w << 16) + w1 * __uint_as_float((unsigned)b.w << 16);
  *(float4 *)(out + (size_t)t * DDIM + c) = r;
}

__global__ __launch_bounds__(64) void aux_k(const int *__restrict__ counts,
                                            const float *__restrict__ probsum,
                                            float *__restrict__ outp) {
  if (threadIdx.x == 0) {
    double s = 0.0;
    for (int e = 0; e < NEXP; ++e)
      s += ((double)counts[e] / (double)TTOK) * ((double)probsum[e] / (double)TTOK);
    *outp = (float)((double)NEXP * s);
  }
}

// ---------------- launch ----------------
extern "C" void kernel_launch(void *const *d_in, const int *in_sizes, int n_in,
                              void *d_out, int out_size, void *d_ws, size_t ws_size,
                              hipStream_t stream) {
  const float *x  = (const float *)d_in[0];
  const float *Wg = (const float *)d_in[1];
  const float *W1 = (const float *)d_in[2];
  const float *b1 = (const float *)d_in[3];
  const float *W2 = (const float *)d_in[4];
  const float *b2 = (const float *)d_in[5];
  float *out = (float *)d_out;

  char *ws = (char *)d_ws;
  const size_t MB = 1ull << 20;
  int   *counts   = (int *)(ws + 0);
  int   *cursors  = (int *)(ws + 64);
  int   *padoff   = (int *)(ws + 128);
  int   *tileexp  = (int *)(ws + 192);
  int   *total    = (int *)(ws + 768);
  float *probsum  = (float *)(ws + 832);
  int   *tok_e    = (int *)(ws + 4096);
  float *tok_w    = (float *)(ws + 36864);
  int   *slot_tok = (int *)(ws + 69632);
  float *slot_w   = (float *)(ws + 147456);
  int   *slot_of  = (int *)(ws + 225280);
  __hip_bfloat16 *xb  = (__hip_bfloat16 *)(ws + 1 * MB);    // 16 MiB  [T][D]
  __hip_bfloat16 *w1t = (__hip_bfloat16 *)(ws + 17 * MB);   // 64 MiB  [E][H][D]
  __hip_bfloat16 *hb  = (__hip_bfloat16 *)(ws + 81 * MB);   // 144 MiB [MAXSLOTS][H]
  __hip_bfloat16 *w2t = (__hip_bfloat16 *)(ws + 1 * MB);    // 64 MiB  [E][D][H] (xb/w1t dead)
  __hip_bfloat16 *yb  = (__hip_bfloat16 *)(ws + 225 * MB);  // 36 MiB  [MAXSLOTS][D]

  zero_meta<<<1, 64, 0, stream>>>(counts, cursors, probsum);
  convert_x<<<8192, 256, 0, stream>>>(x, xb);
  transpose_cvt<<<dim3(16, 64, 8), 256, 0, stream>>>(W1, w1t, DDIM, HDIM);
  router_k<<<TTOK / 4, 256, 0, stream>>>(x, Wg, counts, probsum, tok_e, tok_w);
  offsets_k<<<1, 256, 0, stream>>>(counts, padoff, tileexp, total, slot_tok, slot_w);
  assign_k<<<TTOK / 256, 256, 0, stream>>>(tok_e, tok_w, padoff, cursors, slot_tok, slot_w, slot_of);
  // GEMM1: h = gelu(x@W1+b1): BM=256, BN=256, grid 72x16
  moe_gemmx<256, DDIM, HDIM, true, true, 0><<<dim3(MAXT, HDIM / 256), 512, 0, stream>>>(
      xb, w1t, b1, hb, slot_tok, tileexp, total);
  transpose_cvt<<<dim3(64, 16, 8), 256, 0, stream>>>(W2, w2t, HDIM, DDIM);
  // GEMM2: y = h@W2+b2: BM=128 (2 sub-tiles per 256-tile), BN=256, grid 144x4
  moe_gemmx<128, HDIM, DDIM, false, false, 1><<<dim3(2 * MAXT, DDIM / 256), 512, 0, stream>>>(
      hb, w2t, b2, yb, slot_tok, tileexp, total);
  combine_k<<<TTOK, 256, 0, stream>>>(yb, slot_of, slot_w, out);
  aux_k<<<1, 64, 0, stream>>>(counts, probsum, out + (size_t)TTOK * DDIM);
}